// Round 9
// baseline (3268.994 us; speedup 1.0000x reference)
//
#include <hip/hip_runtime.h>

// TerminalGRU: B=256 T=256 D=512 H=1024 C=128
// Round-9: overlap fusion. The scan (255us/chunk) is latency-bound with ~90%
// idle CU issue slots; cvtx+gates+logits (~1.1ms) were serialized around it.
// Fused kernel (512 blocks): bid<256 = scan chunk c (round-8 proven body);
// bid>=256 = helpers computing gates(c+1) (f32 X direct, no Xc staging) and
// logits(c-1) into double-buffered gx/hsc. Helpers never spin -> no deadlock
// regardless of dispatch; kernel boundaries give cross-chunk visibility.
// ws fallback: if ws_size < fused need (~163MB), run exact round-8 sequence.

#define DEVI __device__ __forceinline__

typedef __bf16 bf16x8 __attribute__((ext_vector_type(8)));
typedef float f32x4 __attribute__((ext_vector_type(4)));
typedef unsigned long long u64;

static constexpr int Bb = 256, Tt = 256, Dd = 512, Hh = 1024, Cc = 128;
static constexpr int G3 = 3072, DC = 640, TC = 32, NC = Tt / TC;
static constexpr int SLOTS = TC + 1;  // 33-slot h ring

DEVI unsigned short f2b(float f) {
  union { float f; unsigned u; } v; v.f = f;
  unsigned r = v.u + 0x7FFFu + ((v.u >> 16) & 1u);
  return (unsigned short)(r >> 16);
}
DEVI float b2f(unsigned short h) {
  union { unsigned u; float f; } v; v.u = ((unsigned)h) << 16; return v.f;
}

union HB { unsigned short s[8]; bf16x8 v; };

// ---------------- prep kernels ----------------

__global__ __launch_bounds__(256) void k_cvt(const float* __restrict__ x,
                                             unsigned short* __restrict__ o, int n) {
  int i = (blockIdx.x * 256 + threadIdx.x) * 8;
  if (i >= n) return;
  float4 a = *(const float4*)(x + i), b = *(const float4*)(x + i + 4);
  uint4 u;
  u.x = (unsigned)f2b(a.x) | ((unsigned)f2b(a.y) << 16);
  u.y = (unsigned)f2b(a.z) | ((unsigned)f2b(a.w) << 16);
  u.z = (unsigned)f2b(b.x) | ((unsigned)f2b(b.y) << 16);
  u.w = (unsigned)f2b(b.z) | ((unsigned)f2b(b.w) << 16);
  *(uint4*)(o + i) = u;
}

__global__ __launch_bounds__(256) void k_cvt_wa(const float* __restrict__ Wih,
                                                unsigned short* __restrict__ Wa) {
  int u = blockIdx.x * 256 + threadIdx.x;
  int g = u >> 6, d = (u & 63) * 8;
  const float* p = Wih + (size_t)g * DC + d;
  float4 a = *(const float4*)p, b = *(const float4*)(p + 4);
  uint4 o;
  o.x = (unsigned)f2b(a.x) | ((unsigned)f2b(a.y) << 16);
  o.y = (unsigned)f2b(a.z) | ((unsigned)f2b(a.w) << 16);
  o.z = (unsigned)f2b(b.x) | ((unsigned)f2b(b.y) << 16);
  o.w = (unsigned)f2b(b.z) | ((unsigned)f2b(b.w) << 16);
  *(uint4*)(Wa + (size_t)g * Dd + d) = o;
}

__global__ __launch_bounds__(256) void k_cvt_wct(const float* __restrict__ Wih,
                                                 unsigned short* __restrict__ WcT) {
  int g = blockIdx.x * 256 + threadIdx.x;
  int c = blockIdx.y;
  WcT[(size_t)c * G3 + g] = f2b(Wih[(size_t)g * DC + Dd + c]);
}

__global__ __launch_bounds__(256) void k_pid(const float* __restrict__ ts,
                                             int* __restrict__ pid) {
  int bt = blockIdx.x * 256 + threadIdx.x;
  int t = bt & (Tt - 1);
  if (t == 0) { pid[bt] = -1; return; }
  const float* p = ts + (size_t)(bt - 1) * Cc;
  int id = 0;
  for (int c = 0; c < Cc; c += 4) {
    float4 v = *(const float4*)(p + c);
    if (v.x > 0.5f) id = c;
    if (v.y > 0.5f) id = c + 1;
    if (v.z > 0.5f) id = c + 2;
    if (v.w > 0.5f) id = c + 3;
  }
  pid[bt] = id;
}

__global__ __launch_bounds__(256) void k_cvtx(const float* __restrict__ gru,
                                              unsigned short* __restrict__ Xc, int t0) {
  int u = (blockIdx.x * 256 + threadIdx.x) * 8;
  int m = u >> 9, d = u & 511;
  int b = m >> 5, tl = m & 31;
  const float* p = gru + ((size_t)(b * Tt + t0 + tl)) * Dd + d;
  float4 a = *(const float4*)p, c = *(const float4*)(p + 4);
  uint4 o;
  o.x = (unsigned)f2b(a.x) | ((unsigned)f2b(a.y) << 16);
  o.y = (unsigned)f2b(a.z) | ((unsigned)f2b(a.w) << 16);
  o.z = (unsigned)f2b(c.x) | ((unsigned)f2b(c.y) << 16);
  o.w = (unsigned)f2b(c.z) | ((unsigned)f2b(c.w) << 16);
  *(uint4*)(Xc + (size_t)m * Dd + d) = o;
}

// ---------------- gates GEMM (bf16 staged A; legacy path) ----------------
__global__ __launch_bounds__(256) void k_gates(const unsigned short* __restrict__ Xc,
                                               const unsigned short* __restrict__ Wa,
                                               const unsigned short* __restrict__ WcT,
                                               const float* __restrict__ bih,
                                               const int* __restrict__ pid,
                                               unsigned short* __restrict__ gx, int t0) {
  int m0 = blockIdx.x * 128, n0 = blockIdx.y * 128;
  int l = threadIdx.x & 63, w = threadIdx.x >> 6;
  int wm = w >> 1, wn = w & 1;
  int r0 = m0 + 64 * wm, c0 = n0 + 64 * wn;
  int lr = l & 15, lk = (l >> 4) * 8;
  f32x4 acc[4][4] = {};
  for (int kk = 0; kk < 16; ++kk) {
    int k = kk * 32 + lk;
    bf16x8 a[4], b[4];
#pragma unroll
    for (int mf = 0; mf < 4; ++mf)
      a[mf] = *(const bf16x8*)(Xc + (size_t)(r0 + 16 * mf + lr) * Dd + k);
#pragma unroll
    for (int nf = 0; nf < 4; ++nf)
      b[nf] = *(const bf16x8*)(Wa + (size_t)(c0 + 16 * nf + lr) * Dd + k);
#pragma unroll
    for (int mf = 0; mf < 4; ++mf)
#pragma unroll
      for (int nf = 0; nf < 4; ++nf)
        acc[mf][nf] = __builtin_amdgcn_mfma_f32_16x16x32_bf16(a[mf], b[nf], acc[mf][nf], 0, 0, 0);
  }
  int ri = (l >> 4) * 4;
  for (int mf = 0; mf < 4; ++mf) {
    int rowb = r0 + 16 * mf + ri;
    int pd[4];
#pragma unroll
    for (int i = 0; i < 4; ++i) {
      int rr = rowb + i;
      pd[i] = pid[(size_t)(rr >> 5) * Tt + t0 + (rr & 31)];
    }
    for (int nf = 0; nf < 4; ++nf) {
      int g = c0 + 16 * nf + lr;
      float bi = bih[g];
#pragma unroll
      for (int i = 0; i < 4; ++i) {
        float v = acc[mf][nf][i] + bi;
        if (pd[i] >= 0) v += b2f(WcT[(size_t)pd[i] * G3 + g]);
        gx[(size_t)(rowb + i) * G3 + g] = f2b(v);
      }
    }
  }
}

// ---------------- gates tile, f32-direct A (fused + prologue) ----------------
DEVI bf16x8 ld_a_f32(const float* __restrict__ X, int m, int t0c, int k) {
  int b = m >> 5, tl = m & 31;
  const float* p = X + ((size_t)(b * Tt + t0c + tl)) * Dd + k;
  float4 x = *(const float4*)p, y = *(const float4*)(p + 4);
  HB r;
  r.s[0] = f2b(x.x); r.s[1] = f2b(x.y); r.s[2] = f2b(x.z); r.s[3] = f2b(x.w);
  r.s[4] = f2b(y.x); r.s[5] = f2b(y.y); r.s[6] = f2b(y.z); r.s[7] = f2b(y.w);
  return r.v;
}

DEVI void gates_tile(int mi, int ni, const float* __restrict__ X,
                     const unsigned short* __restrict__ Wa,
                     const unsigned short* __restrict__ WcT,
                     const float* __restrict__ bih,
                     const int* __restrict__ pid,
                     unsigned short* __restrict__ gx, int t0c) {
  int m0 = mi * 128, n0 = ni * 128;
  int l = threadIdx.x & 63, w = threadIdx.x >> 6;
  int wm = w >> 1, wn = w & 1;
  int r0 = m0 + 64 * wm, c0 = n0 + 64 * wn;
  int lr = l & 15, lk = (l >> 4) * 8;
  f32x4 acc[4][4] = {};
  for (int kk = 0; kk < 16; ++kk) {
    int k = kk * 32 + lk;
    bf16x8 a[4], b[4];
#pragma unroll
    for (int mf = 0; mf < 4; ++mf)
      a[mf] = ld_a_f32(X, r0 + 16 * mf + lr, t0c, k);
#pragma unroll
    for (int nf = 0; nf < 4; ++nf)
      b[nf] = *(const bf16x8*)(Wa + (size_t)(c0 + 16 * nf + lr) * Dd + k);
#pragma unroll
    for (int mf = 0; mf < 4; ++mf)
#pragma unroll
      for (int nf = 0; nf < 4; ++nf)
        acc[mf][nf] = __builtin_amdgcn_mfma_f32_16x16x32_bf16(a[mf], b[nf], acc[mf][nf], 0, 0, 0);
  }
  int ri = (l >> 4) * 4;
  for (int mf = 0; mf < 4; ++mf) {
    int rowb = r0 + 16 * mf + ri;
    int pd[4];
#pragma unroll
    for (int i = 0; i < 4; ++i) {
      int rr = rowb + i;
      pd[i] = pid[(size_t)(rr >> 5) * Tt + t0c + (rr & 31)];
    }
    for (int nf = 0; nf < 4; ++nf) {
      int g = c0 + 16 * nf + lr;
      float bi = bih[g];
#pragma unroll
      for (int i = 0; i < 4; ++i) {
        float v = acc[mf][nf][i] + bi;
        if (pd[i] >= 0) v += b2f(WcT[(size_t)pd[i] * G3 + g]);
        gx[(size_t)(rowb + i) * G3 + g] = f2b(v);
      }
    }
  }
}

__global__ __launch_bounds__(256) void k_gatesF(const float* __restrict__ X,
                                                const unsigned short* __restrict__ Wa,
                                                const unsigned short* __restrict__ WcT,
                                                const float* __restrict__ bih,
                                                const int* __restrict__ pid,
                                                unsigned short* __restrict__ gx, int t0c) {
  gates_tile(blockIdx.x, blockIdx.y, X, Wa, WcT, bih, pid, gx, t0c);
}

// ---------------- logits tile ----------------
DEVI void logits_tile(int blk, const unsigned short* __restrict__ hsc,
                      const unsigned short* __restrict__ Wo,
                      const float* __restrict__ bout,
                      float* __restrict__ out, int t0) {
  int l = threadIdx.x & 63, w = threadIdx.x >> 6;
  int lr = l & 15, lk = (l >> 4) * 8;
  int r0 = blk * 64 + 16 * w;
  f32x4 acc[8] = {};
  for (int kk = 0; kk < 32; ++kk) {
    int k = kk * 32 + lk;
    bf16x8 a = *(const bf16x8*)(hsc + (size_t)(r0 + lr) * Hh + k);
#pragma unroll
    for (int nf = 0; nf < 8; ++nf) {
      bf16x8 b = *(const bf16x8*)(Wo + (size_t)(16 * nf + lr) * Hh + k);
      acc[nf] = __builtin_amdgcn_mfma_f32_16x16x32_bf16(a, b, acc[nf], 0, 0, 0);
    }
  }
  int ri = (l >> 4) * 4;
  for (int nf = 0; nf < 8; ++nf) {
    int c = 16 * nf + lr;
    float bo = bout[c];
#pragma unroll
    for (int i = 0; i < 4; ++i) {
      int m = r0 + ri + i;
      int grow = (m >> 5) * Tt + t0 + (m & 31);
      out[(size_t)grow * Cc + c] = acc[nf][i] + bo;
    }
  }
}

__global__ __launch_bounds__(256) void k_logits(const unsigned short* __restrict__ hsc,
                                                const unsigned short* __restrict__ Wo,
                                                const float* __restrict__ bout,
                                                float* __restrict__ out, int t0) {
  logits_tile(blockIdx.x, hsc, Wo, bout, out, t0);
}

// ---------------- scan body (round-8 proven) ----------------
DEVI void scan_body(const unsigned short* __restrict__ Whh,
                    const float* __restrict__ bhh,
                    const unsigned short* __restrict__ gx,
                    unsigned short* __restrict__ hring,
                    unsigned short* __restrict__ hsc,
                    unsigned int* __restrict__ notify,
                    int t0, float* red) {
  const int tid = threadIdx.x;
  const int l = tid & 63, w = tid >> 6;
  const int bid = blockIdx.x;
  const int xcd = bid & 7, slot = bid >> 3;
  const int mg = xcd >> 1;
  const int gidx = slot * 2 + (xcd & 1);  // block index within group [0,64)
  const int lr = l & 15, lk = (l >> 4) * 8;
  const int hcolBase = 16 * gidx;
  const int ri = (l >> 4) * 4;

  bf16x8 Breg[3][8];
#pragma unroll
  for (int nf = 0; nf < 3; ++nf) {
    int wrow = nf * Hh + hcolBase + lr;
#pragma unroll
    for (int kk = 0; kk < 8; ++kk) {
      int k = 256 * w + 32 * kk + lk;
      Breg[nf][kk] = *(const bf16x8*)(Whh + (size_t)wrow * Hh + k);
    }
  }

  const int erow = tid >> 2, ej0 = (tid & 3) * 4;
  const int eb = 64 * mg + erow;
  const int ecol = hcolBase + ej0;
  const float4 bhr4 = *(const float4*)(bhh + ecol);
  const float4 bhz4 = *(const float4*)(bhh + Hh + ecol);
  const float4 bhn4 = *(const float4*)(bhh + 2 * Hh + ecol);

  u64 hsave = 0;

  for (int tl = 0; tl < TC; ++tl) {
    const int t = t0 + tl;
    const unsigned short* hcur = hring + (size_t)(t % SLOTS) * (Bb * Hh);
    u64* hnq = (u64*)hring + (size_t)((t + 1) % SLOTS) * (Bb * Hh / 4);

    const size_t gxo = (size_t)(eb * TC + tl) * G3;
    uint2 gr = *(const uint2*)(gx + gxo + ecol);
    uint2 gz = *(const uint2*)(gx + gxo + Hh + ecol);
    uint2 gn = *(const uint2*)(gx + gxo + 2 * Hh + ecol);

    if (t > 0) {
      if (w == 0) {
        const unsigned int* np = notify + (mg << 6);
        for (;;) {
          unsigned int v = __hip_atomic_load(np + l, __ATOMIC_RELAXED,
                                             __HIP_MEMORY_SCOPE_AGENT);
          if (__all((int)(v >= (unsigned)t))) break;
          __builtin_amdgcn_s_sleep(2);
        }
      }
      __syncthreads();
    }
    asm volatile("" ::: "memory");

    u64 hprev = (tl == 0) ? *(const u64*)(hcur + (size_t)eb * Hh + ecol) : hsave;

    f32x4 acc[4][3] = {};
#pragma unroll
    for (int kk = 0; kk < 8; ++kk) {
      int k = 256 * w + 32 * kk + lk;
      bf16x8 a[4];
#pragma unroll
      for (int mf = 0; mf < 4; ++mf)
        a[mf] = *(const bf16x8*)(hcur + (size_t)(64 * mg + 16 * mf + lr) * Hh + k);
#pragma unroll
      for (int mf = 0; mf < 4; ++mf)
#pragma unroll
        for (int nf = 0; nf < 3; ++nf)
          acc[mf][nf] = __builtin_amdgcn_mfma_f32_16x16x32_bf16(a[mf], Breg[nf][kk], acc[mf][nf], 0, 0, 0);
    }

#pragma unroll
    for (int mf = 0; mf < 4; ++mf)
#pragma unroll
      for (int nf = 0; nf < 3; ++nf)
#pragma unroll
        for (int i = 0; i < 4; ++i)
          red[(w * 64 + 16 * mf + ri + i) * 52 + 16 * nf + lr] = acc[mf][nf][i];
    __syncthreads();

    f32x4 vr = {}, vz = {}, vn = {};
#pragma unroll
    for (int w2 = 0; w2 < 4; ++w2) {
      const float* rp = &red[(w2 * 64 + erow) * 52];
      vr += *(const f32x4*)(rp + ej0);
      vz += *(const f32x4*)(rp + 16 + ej0);
      vn += *(const f32x4*)(rp + 32 + ej0);
    }
    unsigned short grs[4] = {(unsigned short)gr.x, (unsigned short)(gr.x >> 16),
                             (unsigned short)gr.y, (unsigned short)(gr.y >> 16)};
    unsigned short gzs[4] = {(unsigned short)gz.x, (unsigned short)(gz.x >> 16),
                             (unsigned short)gz.y, (unsigned short)(gz.y >> 16)};
    unsigned short gns[4] = {(unsigned short)gn.x, (unsigned short)(gn.x >> 16),
                             (unsigned short)gn.y, (unsigned short)(gn.y >> 16)};
    u64 ho = 0;
#pragma unroll
    for (int i = 0; i < 4; ++i) {
      float hr = vr[i] + (&bhr4.x)[i];
      float hz = vz[i] + (&bhz4.x)[i];
      float hn = vn[i] + (&bhn4.x)[i];
      float xr = b2f(grs[i]), xz = b2f(gzs[i]), xn = b2f(gns[i]);
      float rg = 1.f / (1.f + __expf(-(xr + hr)));
      float zg = 1.f / (1.f + __expf(-(xz + hz)));
      float pre = xn + rg * hn;
      pre = fminf(fmaxf(pre, -15.f), 15.f);
      float e = __expf(-2.f * pre);
      float ng = (1.f - e) / (1.f + e);
      float hp = b2f((unsigned short)(hprev >> (16 * i)));
      float hv = (1.f - zg) * ng + zg * hp;
      ho |= (u64)f2b(hv) << (16 * i);
    }
    __hip_atomic_store(hnq + ((size_t)eb * Hh + ecol) / 4, ho,
                       __ATOMIC_RELAXED, __HIP_MEMORY_SCOPE_AGENT);
    hsave = ho;

    asm volatile("s_waitcnt vmcnt(0)" ::: "memory");
    __syncthreads();
    if (tid == 0)
      __hip_atomic_store(notify + (mg << 6) + gidx, (unsigned)(t + 1),
                         __ATOMIC_RELAXED, __HIP_MEMORY_SCOPE_AGENT);
    *(u64*)(hsc + (size_t)(eb * TC + tl) * Hh + ecol) = ho;
  }
}

// ---------------- fused kernel: scan + helpers ----------------
__global__ __launch_bounds__(256, 2) void k_fused(
    const unsigned short* __restrict__ Whh, const float* __restrict__ bhh,
    const unsigned short* __restrict__ gxCur, unsigned short* __restrict__ hring,
    unsigned short* __restrict__ hscCur, unsigned int* __restrict__ nfy, int t0,
    const float* __restrict__ gruX, const unsigned short* __restrict__ Wa,
    const unsigned short* __restrict__ WcT, const float* __restrict__ bih,
    const int* __restrict__ pid, unsigned short* __restrict__ gxNext, int doGates,
    const unsigned short* __restrict__ hscPrev, const unsigned short* __restrict__ Wob,
    const float* __restrict__ bou, float* __restrict__ outp, int doLogits) {
  __shared__ float red[4 * 64 * 52];
  if (blockIdx.x < 256) {
    scan_body(Whh, bhh, gxCur, hring, hscCur, nfy, t0, red);
    return;
  }
  int h = blockIdx.x - 256;
  if (doGates) {
    for (int tix = h; tix < 64 * 24; tix += 256)
      gates_tile(tix & 63, tix >> 6, gruX, Wa, WcT, bih, pid, gxNext, t0 + TC);
  }
  if (doLogits && h < 128)
    logits_tile(h, hscPrev, Wob, bou, outp, t0 - TC);
}

// ---------------- launch ----------------
extern "C" void kernel_launch(void* const* d_in, const int* in_sizes, int n_in,
                              void* d_out, int out_size, void* d_ws, size_t ws_size,
                              hipStream_t stream) {
  const float* gru = (const float*)d_in[0];
  const float* ts  = (const float*)d_in[1];
  const float* Wih = (const float*)d_in[2];
  const float* bih = (const float*)d_in[3];
  const float* Whh = (const float*)d_in[4];
  const float* bhh = (const float*)d_in[5];
  const float* Wou = (const float*)d_in[6];
  const float* bou = (const float*)d_in[7];
  float* out = (float*)d_out;

  char* ws = (char*)d_ws;
  size_t off = 0;
  auto alloc = [&](size_t bytes) -> void* {
    void* p = ws + off;
    off += (bytes + 255) & ~(size_t)255;
    return p;
  };
  const size_t gxB = (size_t)Bb * TC * G3 * 2;   // 50.3MB
  const size_t hscB = (size_t)Bb * TC * Hh * 2;  // 16.8MB
  const size_t XcB = (size_t)Bb * TC * Dd * 2;   // 8.4MB

  unsigned short* Wa    = (unsigned short*)alloc((size_t)G3 * Dd * 2);
  unsigned short* WcT   = (unsigned short*)alloc((size_t)Cc * G3 * 2);
  unsigned short* Whb   = (unsigned short*)alloc((size_t)G3 * Hh * 2);
  unsigned short* Wob   = (unsigned short*)alloc((size_t)Cc * Hh * 2);
  int*            pid   = (int*)alloc((size_t)Bb * Tt * 4);
  unsigned short* hring = (unsigned short*)alloc((size_t)SLOTS * Bb * Hh * 2);
  unsigned int*   nfy   = (unsigned int*)alloc((size_t)4 * 64 * 4);
  size_t commonOff = off;
  bool fused = (commonOff + 2 * (gxB + 256) + 2 * (hscB + 256)) <= ws_size;

  // common prep
  k_cvt<<<(G3 * Hh) / 2048, 256, 0, stream>>>(Whh, Whb, G3 * Hh);
  k_cvt<<<(Cc * Hh) / 2048, 256, 0, stream>>>(Wou, Wob, Cc * Hh);
  k_cvt_wa<<<(G3 * 64) / 256, 256, 0, stream>>>(Wih, Wa);
  k_cvt_wct<<<dim3(G3 / 256, Cc), 256, 0, stream>>>(Wih, WcT);
  k_pid<<<(Bb * Tt) / 256, 256, 0, stream>>>(ts, pid);
  hipMemsetAsync(hring, 0, (size_t)Bb * Hh * 2, stream);  // slot 0 = h(0) = 0
  hipMemsetAsync(nfy, 0, (size_t)4 * 64 * 4, stream);

  if (fused) {
    unsigned short* gxb[2]  = { (unsigned short*)alloc(gxB),  (unsigned short*)alloc(gxB)  };
    unsigned short* hscb[2] = { (unsigned short*)alloc(hscB), (unsigned short*)alloc(hscB) };
    // prologue: gates for chunk 0
    k_gatesF<<<dim3(64, 24), 256, 0, stream>>>(gru, Wa, WcT, bih, pid, gxb[0], 0);
    for (int c = 0; c < NC; ++c) {
      int t0 = c * TC;
      k_fused<<<512, 256, 0, stream>>>(
          Whb, bhh, gxb[c & 1], hring, hscb[c & 1], nfy, t0,
          gru, Wa, WcT, bih, pid, gxb[(c + 1) & 1], (c + 1 < NC) ? 1 : 0,
          hscb[(c & 1) ^ 1], Wob, bou, out, (c >= 1) ? 1 : 0);
    }
    // epilogue: logits for chunk 7
    k_logits<<<(Bb * TC) / 64, 256, 0, stream>>>(hscb[(NC - 1) & 1], Wob, bou, out,
                                                 (NC - 1) * TC);
  } else {
    // legacy round-8 sequence (proven <=104MB)
    unsigned short* Xc  = (unsigned short*)alloc(XcB);
    unsigned short* gx  = (unsigned short*)alloc(gxB);
    unsigned short* hsc = (unsigned short*)alloc(hscB);
    if (ws_size < off) return;
    for (int c = 0; c < NC; ++c) {
      int t0 = c * TC;
      k_cvtx<<<(Bb * TC * Dd) / 2048, 256, 0, stream>>>(gru, Xc, t0);
      k_gates<<<dim3((Bb * TC) / 128, G3 / 128), 256, 0, stream>>>(Xc, Wa, WcT, bih, pid, gx, t0);
      k_fused<<<256, 256, 0, stream>>>(
          Whb, bhh, gx, hring, hsc, nfy, t0,
          gru, Wa, WcT, bih, pid, (unsigned short*)nullptr, 0,
          (const unsigned short*)nullptr, Wob, bou, out, 0);
      k_logits<<<(Bb * TC) / 64, 256, 0, stream>>>(hsc, Wob, bou, out, t0);
    }
  }
}

// Round 10
// 2809.744 us; speedup vs baseline: 1.1634x; 1.1634x over previous
//
#include <hip/hip_runtime.h>

// TerminalGRU: B=256 T=256 D=512 H=1024 C=128
// Round-10: revert co-resident fusion (measured interference). Serialized
// pipeline, 3 changes:
//  1) scan geometry: 8 groups x 32 rows; 32 blocks/group each owning 32 hcols
//     (round-2 proven tile: Breg[6][8], acc[2][6]). Fan-in 64->32; group's 32
//     blocks land on one XCD (bid&7=group) -> h re-reads L2-local.
//  2) all-wave poll, no s_sleep, no post-poll barrier (shorter notify chain).
//  3) no cvtx (gates reads f32 X direct, f2b-identical); logits(c)+gates(c+1)
//     merged into one 1664-block dispatch; gx double-buffered.

#define DEVI __device__ __forceinline__

typedef __bf16 bf16x8 __attribute__((ext_vector_type(8)));
typedef float f32x4 __attribute__((ext_vector_type(4)));
typedef unsigned long long u64;

static constexpr int Bb = 256, Tt = 256, Dd = 512, Hh = 1024, Cc = 128;
static constexpr int G3 = 3072, DC = 640, TC = 32, NC = Tt / TC;
static constexpr int SLOTS = TC + 1;  // 33-slot h ring

DEVI unsigned short f2b(float f) {
  union { float f; unsigned u; } v; v.f = f;
  unsigned r = v.u + 0x7FFFu + ((v.u >> 16) & 1u);
  return (unsigned short)(r >> 16);
}
DEVI float b2f(unsigned short h) {
  union { unsigned u; float f; } v; v.u = ((unsigned)h) << 16; return v.f;
}

union HB { unsigned short s[8]; bf16x8 v; };

// ---------------- prep kernels ----------------

__global__ __launch_bounds__(256) void k_cvt(const float* __restrict__ x,
                                             unsigned short* __restrict__ o, int n) {
  int i = (blockIdx.x * 256 + threadIdx.x) * 8;
  if (i >= n) return;
  float4 a = *(const float4*)(x + i), b = *(const float4*)(x + i + 4);
  uint4 u;
  u.x = (unsigned)f2b(a.x) | ((unsigned)f2b(a.y) << 16);
  u.y = (unsigned)f2b(a.z) | ((unsigned)f2b(a.w) << 16);
  u.z = (unsigned)f2b(b.x) | ((unsigned)f2b(b.y) << 16);
  u.w = (unsigned)f2b(b.z) | ((unsigned)f2b(b.w) << 16);
  *(uint4*)(o + i) = u;
}

__global__ __launch_bounds__(256) void k_cvt_wa(const float* __restrict__ Wih,
                                                unsigned short* __restrict__ Wa) {
  int u = blockIdx.x * 256 + threadIdx.x;
  int g = u >> 6, d = (u & 63) * 8;
  const float* p = Wih + (size_t)g * DC + d;
  float4 a = *(const float4*)p, b = *(const float4*)(p + 4);
  uint4 o;
  o.x = (unsigned)f2b(a.x) | ((unsigned)f2b(a.y) << 16);
  o.y = (unsigned)f2b(a.z) | ((unsigned)f2b(a.w) << 16);
  o.z = (unsigned)f2b(b.x) | ((unsigned)f2b(b.y) << 16);
  o.w = (unsigned)f2b(b.z) | ((unsigned)f2b(b.w) << 16);
  *(uint4*)(Wa + (size_t)g * Dd + d) = o;
}

__global__ __launch_bounds__(256) void k_cvt_wct(const float* __restrict__ Wih,
                                                 unsigned short* __restrict__ WcT) {
  int g = blockIdx.x * 256 + threadIdx.x;
  int c = blockIdx.y;
  WcT[(size_t)c * G3 + g] = f2b(Wih[(size_t)g * DC + Dd + c]);
}

__global__ __launch_bounds__(256) void k_pid(const float* __restrict__ ts,
                                             int* __restrict__ pid) {
  int bt = blockIdx.x * 256 + threadIdx.x;
  int t = bt & (Tt - 1);
  if (t == 0) { pid[bt] = -1; return; }
  const float* p = ts + (size_t)(bt - 1) * Cc;
  int id = 0;
  for (int c = 0; c < Cc; c += 4) {
    float4 v = *(const float4*)(p + c);
    if (v.x > 0.5f) id = c;
    if (v.y > 0.5f) id = c + 1;
    if (v.z > 0.5f) id = c + 2;
    if (v.w > 0.5f) id = c + 3;
  }
  pid[bt] = id;
}

// ---------------- gates tile (f32-direct A) ----------------
DEVI bf16x8 ld_a_f32(const float* __restrict__ X, int m, int t0c, int k) {
  int b = m >> 5, tl = m & 31;
  const float* p = X + ((size_t)(b * Tt + t0c + tl)) * Dd + k;
  float4 x = *(const float4*)p, y = *(const float4*)(p + 4);
  HB r;
  r.s[0] = f2b(x.x); r.s[1] = f2b(x.y); r.s[2] = f2b(x.z); r.s[3] = f2b(x.w);
  r.s[4] = f2b(y.x); r.s[5] = f2b(y.y); r.s[6] = f2b(y.z); r.s[7] = f2b(y.w);
  return r.v;
}

DEVI void gates_tile(int mi, int ni, const float* __restrict__ X,
                     const unsigned short* __restrict__ Wa,
                     const unsigned short* __restrict__ WcT,
                     const float* __restrict__ bih,
                     const int* __restrict__ pid,
                     unsigned short* __restrict__ gx, int t0c) {
  int m0 = mi * 128, n0 = ni * 128;
  int l = threadIdx.x & 63, w = threadIdx.x >> 6;
  int wm = w >> 1, wn = w & 1;
  int r0 = m0 + 64 * wm, c0 = n0 + 64 * wn;
  int lr = l & 15, lk = (l >> 4) * 8;
  f32x4 acc[4][4] = {};
  for (int kk = 0; kk < 16; ++kk) {
    int k = kk * 32 + lk;
    bf16x8 a[4], b[4];
#pragma unroll
    for (int mf = 0; mf < 4; ++mf)
      a[mf] = ld_a_f32(X, r0 + 16 * mf + lr, t0c, k);
#pragma unroll
    for (int nf = 0; nf < 4; ++nf)
      b[nf] = *(const bf16x8*)(Wa + (size_t)(c0 + 16 * nf + lr) * Dd + k);
#pragma unroll
    for (int mf = 0; mf < 4; ++mf)
#pragma unroll
      for (int nf = 0; nf < 4; ++nf)
        acc[mf][nf] = __builtin_amdgcn_mfma_f32_16x16x32_bf16(a[mf], b[nf], acc[mf][nf], 0, 0, 0);
  }
  int ri = (l >> 4) * 4;
  for (int mf = 0; mf < 4; ++mf) {
    int rowb = r0 + 16 * mf + ri;
    int pd[4];
#pragma unroll
    for (int i = 0; i < 4; ++i) {
      int rr = rowb + i;
      pd[i] = pid[(size_t)(rr >> 5) * Tt + t0c + (rr & 31)];
    }
    for (int nf = 0; nf < 4; ++nf) {
      int g = c0 + 16 * nf + lr;
      float bi = bih[g];
#pragma unroll
      for (int i = 0; i < 4; ++i) {
        float v = acc[mf][nf][i] + bi;
        if (pd[i] >= 0) v += b2f(WcT[(size_t)pd[i] * G3 + g]);
        gx[(size_t)(rowb + i) * G3 + g] = f2b(v);
      }
    }
  }
}

__global__ __launch_bounds__(256) void k_gatesF(const float* __restrict__ X,
                                                const unsigned short* __restrict__ Wa,
                                                const unsigned short* __restrict__ WcT,
                                                const float* __restrict__ bih,
                                                const int* __restrict__ pid,
                                                unsigned short* __restrict__ gx, int t0c) {
  gates_tile(blockIdx.x, blockIdx.y, X, Wa, WcT, bih, pid, gx, t0c);
}

// ---------------- logits tile ----------------
DEVI void logits_tile(int blk, const unsigned short* __restrict__ hsc,
                      const unsigned short* __restrict__ Wo,
                      const float* __restrict__ bout,
                      float* __restrict__ out, int t0) {
  int l = threadIdx.x & 63, w = threadIdx.x >> 6;
  int lr = l & 15, lk = (l >> 4) * 8;
  int r0 = blk * 64 + 16 * w;
  f32x4 acc[8] = {};
  for (int kk = 0; kk < 32; ++kk) {
    int k = kk * 32 + lk;
    bf16x8 a = *(const bf16x8*)(hsc + (size_t)(r0 + lr) * Hh + k);
#pragma unroll
    for (int nf = 0; nf < 8; ++nf) {
      bf16x8 b = *(const bf16x8*)(Wo + (size_t)(16 * nf + lr) * Hh + k);
      acc[nf] = __builtin_amdgcn_mfma_f32_16x16x32_bf16(a, b, acc[nf], 0, 0, 0);
    }
  }
  int ri = (l >> 4) * 4;
  for (int nf = 0; nf < 8; ++nf) {
    int c = 16 * nf + lr;
    float bo = bout[c];
#pragma unroll
    for (int i = 0; i < 4; ++i) {
      int m = r0 + ri + i;
      int grow = (m >> 5) * Tt + t0 + (m & 31);
      out[(size_t)grow * Cc + c] = acc[nf][i] + bo;
    }
  }
}

// ---------------- combo: gates(c+1) + logits(c) in one dispatch ----------------
__global__ __launch_bounds__(256) void k_combo(
    const float* __restrict__ X, const unsigned short* __restrict__ Wa,
    const unsigned short* __restrict__ WcT, const float* __restrict__ bih,
    const int* __restrict__ pid, unsigned short* __restrict__ gxNext, int doGates,
    const unsigned short* __restrict__ hsc, const unsigned short* __restrict__ Wob,
    const float* __restrict__ bou, float* __restrict__ outp, int t0) {
  int bid = blockIdx.x;
  if (bid < 1536) {
    if (doGates)
      gates_tile(bid & 63, bid >> 6, X, Wa, WcT, bih, pid, gxNext, t0 + TC);
  } else {
    logits_tile(bid - 1536, hsc, Wob, bou, outp, t0);
  }
}

// ---------------- recurrent scan chunk ----------------
// 256 blocks x 256 threads. mg = bid&7 (group/XCD, rows [32mg,+32)),
// cb = bid>>3 (hcols [32cb,+32)). Wave w: K-slice [256w,+256).
// notify[mg][32] epoch words; ALL waves poll (no sleep, no post-poll barrier).
__global__ __launch_bounds__(256, 1) void k_scan(const unsigned short* __restrict__ Whh,
                                                 const float* __restrict__ bhh,
                                                 const unsigned short* __restrict__ gx,
                                                 unsigned short* __restrict__ hring,
                                                 unsigned short* __restrict__ hsc,
                                                 unsigned int* __restrict__ notify,
                                                 int t0) {
  __shared__ float red[4 * 32 * 100];  // [wave][row32][3*32 pad100] = 51.2KB
  const int tid = threadIdx.x;
  const int l = tid & 63, w = tid >> 6;
  const int bid = blockIdx.x;
  const int mg = bid & 7, cb = bid >> 3;
  const int lr = l & 15, lk = (l >> 4) * 8;
  const int hcolBase = 32 * cb;
  const int ri = (l >> 4) * 4;

  // resident W_hh fragments: 3 gates x 2 col-halves x 8 k-steps
  bf16x8 Breg[6][8];
#pragma unroll
  for (int nf = 0; nf < 6; ++nf) {
    int wrow = (nf >> 1) * Hh + hcolBase + (nf & 1) * 16 + lr;
#pragma unroll
    for (int kk = 0; kk < 8; ++kk) {
      int k = 256 * w + 32 * kk + lk;
      Breg[nf][kk] = *(const bf16x8*)(Whh + (size_t)wrow * Hh + k);
    }
  }

  // epilogue mapping: thread -> 1 row x 4 cols (8-byte h I/O)
  const int erow = tid >> 3, ej0 = (tid & 7) * 4;
  const int eb = 32 * mg + erow;
  const int ecol = hcolBase + ej0;
  const float4 bhr4 = *(const float4*)(bhh + ecol);
  const float4 bhz4 = *(const float4*)(bhh + Hh + ecol);
  const float4 bhn4 = *(const float4*)(bhh + 2 * Hh + ecol);

  u64 hsave = 0;  // own h slice carried in registers across steps

  for (int tl = 0; tl < TC; ++tl) {
    const int t = t0 + tl;
    const unsigned short* hcur = hring + (size_t)(t % SLOTS) * (Bb * Hh);
    u64* hnq = (u64*)hring + (size_t)((t + 1) % SLOTS) * (Bb * Hh / 4);

    // prefetch gx for this step (independent of the wait)
    const size_t gxo = (size_t)(eb * TC + tl) * G3;
    uint2 gr = *(const uint2*)(gx + gxo + ecol);
    uint2 gz = *(const uint2*)(gx + gxo + Hh + ecol);
    uint2 gn = *(const uint2*)(gx + gxo + 2 * Hh + ecol);

    // wait: all 32 blocks of this group produced h[t]; every wave polls
    if (t > 0) {
      const unsigned int* np = notify + (mg << 6) + (l & 31);
      for (;;) {
        unsigned int v = __hip_atomic_load(np, __ATOMIC_RELAXED,
                                           __HIP_MEMORY_SCOPE_AGENT);
        if (__all((int)(v >= (unsigned)t))) break;
      }
    }
    asm volatile("" ::: "memory");

    u64 hprev = (tl == 0) ? *(const u64*)(hcur + (size_t)eb * Hh + ecol) : hsave;

    f32x4 acc[2][6] = {};
#pragma unroll
    for (int kk = 0; kk < 8; ++kk) {
      int k = 256 * w + 32 * kk + lk;
      bf16x8 a[2];
#pragma unroll
      for (int mf = 0; mf < 2; ++mf)
        a[mf] = *(const bf16x8*)(hcur + (size_t)(32 * mg + 16 * mf + lr) * Hh + k);
#pragma unroll
      for (int mf = 0; mf < 2; ++mf)
#pragma unroll
        for (int nf = 0; nf < 6; ++nf)
          acc[mf][nf] = __builtin_amdgcn_mfma_f32_16x16x32_bf16(a[mf], Breg[nf][kk], acc[mf][nf], 0, 0, 0);
    }

    // partials -> LDS (col = gate*32 + half*16 + lr)
#pragma unroll
    for (int mf = 0; mf < 2; ++mf)
#pragma unroll
      for (int nf = 0; nf < 6; ++nf)
#pragma unroll
        for (int i = 0; i < 4; ++i)
          red[(w * 32 + 16 * mf + ri + i) * 100 + (nf >> 1) * 32 + (nf & 1) * 16 + lr] = acc[mf][nf][i];
    __syncthreads();

    // reduce 4 wave-partials + gate math, 1 row x 4 cols per thread
    f32x4 vr = {}, vz = {}, vn = {};
#pragma unroll
    for (int w2 = 0; w2 < 4; ++w2) {
      const float* rp = &red[(w2 * 32 + erow) * 100];
      vr += *(const f32x4*)(rp + ej0);
      vz += *(const f32x4*)(rp + 32 + ej0);
      vn += *(const f32x4*)(rp + 64 + ej0);
    }
    unsigned short grs[4] = {(unsigned short)gr.x, (unsigned short)(gr.x >> 16),
                             (unsigned short)gr.y, (unsigned short)(gr.y >> 16)};
    unsigned short gzs[4] = {(unsigned short)gz.x, (unsigned short)(gz.x >> 16),
                             (unsigned short)gz.y, (unsigned short)(gz.y >> 16)};
    unsigned short gns[4] = {(unsigned short)gn.x, (unsigned short)(gn.x >> 16),
                             (unsigned short)gn.y, (unsigned short)(gn.y >> 16)};
    u64 ho = 0;
#pragma unroll
    for (int i = 0; i < 4; ++i) {
      float hr = vr[i] + (&bhr4.x)[i];
      float hz = vz[i] + (&bhz4.x)[i];
      float hn = vn[i] + (&bhn4.x)[i];
      float xr = b2f(grs[i]), xz = b2f(gzs[i]), xn = b2f(gns[i]);
      float rg = 1.f / (1.f + __expf(-(xr + hr)));
      float zg = 1.f / (1.f + __expf(-(xz + hz)));
      float pre = xn + rg * hn;
      pre = fminf(fmaxf(pre, -15.f), 15.f);
      float e = __expf(-2.f * pre);
      float ng = (1.f - e) / (1.f + e);
      float hp = b2f((unsigned short)(hprev >> (16 * i)));
      float hv = (1.f - zg) * ng + zg * hp;
      ho |= (u64)f2b(hv) << (16 * i);
    }
    // h output: MALL-visible store (consumers' caches hold no copy of this line)
    __hip_atomic_store(hnq + ((size_t)eb * Hh + ecol) / 4, ho,
                       __ATOMIC_RELAXED, __HIP_MEMORY_SCOPE_AGENT);
    hsave = ho;

    asm volatile("s_waitcnt vmcnt(0)" ::: "memory");  // h stores acked at MALL
    __syncthreads();  // all waves drained; also protects red[] reuse
    if (tid == 0)
      __hip_atomic_store(notify + (mg << 6) + cb, (unsigned)(t + 1),
                         __ATOMIC_RELAXED, __HIP_MEMORY_SCOPE_AGENT);
    // history write AFTER notify -- off the critical path
    *(u64*)(hsc + (size_t)(eb * TC + tl) * Hh + ecol) = ho;
  }
}

// ---------------- launch ----------------
extern "C" void kernel_launch(void* const* d_in, const int* in_sizes, int n_in,
                              void* d_out, int out_size, void* d_ws, size_t ws_size,
                              hipStream_t stream) {
  const float* gru = (const float*)d_in[0];
  const float* ts  = (const float*)d_in[1];
  const float* Wih = (const float*)d_in[2];
  const float* bih = (const float*)d_in[3];
  const float* Whh = (const float*)d_in[4];
  const float* bhh = (const float*)d_in[5];
  const float* Wou = (const float*)d_in[6];
  const float* bou = (const float*)d_in[7];
  float* out = (float*)d_out;

  char* ws = (char*)d_ws;
  size_t off = 0;
  auto alloc = [&](size_t bytes) -> void* {
    void* p = ws + off;
    off += (bytes + 255) & ~(size_t)255;
    return p;
  };
  unsigned short* Wa    = (unsigned short*)alloc((size_t)G3 * Dd * 2);
  unsigned short* WcT   = (unsigned short*)alloc((size_t)Cc * G3 * 2);
  unsigned short* Whb   = (unsigned short*)alloc((size_t)G3 * Hh * 2);
  unsigned short* Wob   = (unsigned short*)alloc((size_t)Cc * Hh * 2);
  int*            pid   = (int*)alloc((size_t)Bb * Tt * 4);
  unsigned short* hring = (unsigned short*)alloc((size_t)SLOTS * Bb * Hh * 2);
  unsigned int*   nfy   = (unsigned int*)alloc((size_t)8 * 64 * 4);
  unsigned short* gxb0  = (unsigned short*)alloc((size_t)Bb * TC * G3 * 2);
  unsigned short* gxb1  = (unsigned short*)alloc((size_t)Bb * TC * G3 * 2);
  unsigned short* hsc   = (unsigned short*)alloc((size_t)Bb * TC * Hh * 2);
  if (ws_size < off) return;
  unsigned short* gxb[2] = { gxb0, gxb1 };

  k_cvt<<<(G3 * Hh) / 2048, 256, 0, stream>>>(Whh, Whb, G3 * Hh);
  k_cvt<<<(Cc * Hh) / 2048, 256, 0, stream>>>(Wou, Wob, Cc * Hh);
  k_cvt_wa<<<(G3 * 64) / 256, 256, 0, stream>>>(Wih, Wa);
  k_cvt_wct<<<dim3(G3 / 256, Cc), 256, 0, stream>>>(Wih, WcT);
  k_pid<<<(Bb * Tt) / 256, 256, 0, stream>>>(ts, pid);
  hipMemsetAsync(hring, 0, (size_t)Bb * Hh * 2, stream);  // slot 0 = h(0) = 0
  hipMemsetAsync(nfy, 0, (size_t)8 * 64 * 4, stream);

  // prologue: gates for chunk 0
  k_gatesF<<<dim3(64, 24), 256, 0, stream>>>(gru, Wa, WcT, bih, pid, gxb[0], 0);

  for (int c = 0; c < NC; ++c) {
    int t0 = c * TC;
    k_scan<<<dim3(256), dim3(256), 0, stream>>>(Whb, bhh, gxb[c & 1], hring, hsc, nfy, t0);
    k_combo<<<dim3(1664), dim3(256), 0, stream>>>(
        gru, Wa, WcT, bih, pid, gxb[(c + 1) & 1], (c + 1 < NC) ? 1 : 0,
        hsc, Wob, bou, out, t0);
  }
}

// Round 11
// 2670.616 us; speedup vs baseline: 1.2241x; 1.0521x over previous
//
#include <hip/hip_runtime.h>

// TerminalGRU: B=256 T=256 D=512 H=1024 C=128
// Round-11: combo was the long pole (191us: f32-direct A = 32B loads + ~24
// VALU cvt ops per fragment inside the GEMM loop, x24 N-tile redundancy).
// Now: X->bf16 ONCE up front (Xb, 67MB); gates A-loads are single 16B bf16
// loads at global rows (b*Tt+t0+tl). gx single-buffered (stream-serialized
// reuse). Scan untouched (round-10 proven, ~140us/chunk).
// Pipeline: prep+cvtX -> gates(0) -> loop{ scan(c); combo: gates(c+1)+logits(c) }

#define DEVI __device__ __forceinline__

typedef __bf16 bf16x8 __attribute__((ext_vector_type(8)));
typedef float f32x4 __attribute__((ext_vector_type(4)));
typedef unsigned long long u64;

static constexpr int Bb = 256, Tt = 256, Dd = 512, Hh = 1024, Cc = 128;
static constexpr int G3 = 3072, DC = 640, TC = 32, NC = Tt / TC;
static constexpr int SLOTS = TC + 1;  // 33-slot h ring

DEVI unsigned short f2b(float f) {
  union { float f; unsigned u; } v; v.f = f;
  unsigned r = v.u + 0x7FFFu + ((v.u >> 16) & 1u);
  return (unsigned short)(r >> 16);
}
DEVI float b2f(unsigned short h) {
  union { unsigned u; float f; } v; v.u = ((unsigned)h) << 16; return v.f;
}

// ---------------- prep kernels ----------------

__global__ __launch_bounds__(256) void k_cvt(const float* __restrict__ x,
                                             unsigned short* __restrict__ o, int n) {
  int i = (blockIdx.x * 256 + threadIdx.x) * 8;
  if (i >= n) return;
  float4 a = *(const float4*)(x + i), b = *(const float4*)(x + i + 4);
  uint4 u;
  u.x = (unsigned)f2b(a.x) | ((unsigned)f2b(a.y) << 16);
  u.y = (unsigned)f2b(a.z) | ((unsigned)f2b(a.w) << 16);
  u.z = (unsigned)f2b(b.x) | ((unsigned)f2b(b.y) << 16);
  u.w = (unsigned)f2b(b.z) | ((unsigned)f2b(b.w) << 16);
  *(uint4*)(o + i) = u;
}

__global__ __launch_bounds__(256) void k_cvt_wa(const float* __restrict__ Wih,
                                                unsigned short* __restrict__ Wa) {
  int u = blockIdx.x * 256 + threadIdx.x;
  int g = u >> 6, d = (u & 63) * 8;
  const float* p = Wih + (size_t)g * DC + d;
  float4 a = *(const float4*)p, b = *(const float4*)(p + 4);
  uint4 o;
  o.x = (unsigned)f2b(a.x) | ((unsigned)f2b(a.y) << 16);
  o.y = (unsigned)f2b(a.z) | ((unsigned)f2b(a.w) << 16);
  o.z = (unsigned)f2b(b.x) | ((unsigned)f2b(b.y) << 16);
  o.w = (unsigned)f2b(b.z) | ((unsigned)f2b(b.w) << 16);
  *(uint4*)(Wa + (size_t)g * Dd + d) = o;
}

__global__ __launch_bounds__(256) void k_cvt_wct(const float* __restrict__ Wih,
                                                 unsigned short* __restrict__ WcT) {
  int g = blockIdx.x * 256 + threadIdx.x;
  int c = blockIdx.y;
  WcT[(size_t)c * G3 + g] = f2b(Wih[(size_t)g * DC + Dd + c]);
}

__global__ __launch_bounds__(256) void k_pid(const float* __restrict__ ts,
                                             int* __restrict__ pid) {
  int bt = blockIdx.x * 256 + threadIdx.x;
  int t = bt & (Tt - 1);
  if (t == 0) { pid[bt] = -1; return; }
  const float* p = ts + (size_t)(bt - 1) * Cc;
  int id = 0;
  for (int c = 0; c < Cc; c += 4) {
    float4 v = *(const float4*)(p + c);
    if (v.x > 0.5f) id = c;
    if (v.y > 0.5f) id = c + 1;
    if (v.z > 0.5f) id = c + 2;
    if (v.w > 0.5f) id = c + 3;
  }
  pid[bt] = id;
}

// ---------------- gates tile (bf16 staged A, global-row indexed) ----------------
DEVI bf16x8 ld_a(const unsigned short* __restrict__ Xb, int m, int t0c, int k) {
  int b = m >> 5, tl = m & 31;
  return *(const bf16x8*)(Xb + ((size_t)(b * Tt + t0c + tl)) * Dd + k);
}

DEVI void gates_tile(int mi, int ni, const unsigned short* __restrict__ Xb,
                     const unsigned short* __restrict__ Wa,
                     const unsigned short* __restrict__ WcT,
                     const float* __restrict__ bih,
                     const int* __restrict__ pid,
                     unsigned short* __restrict__ gx, int t0c) {
  int m0 = mi * 128, n0 = ni * 128;
  int l = threadIdx.x & 63, w = threadIdx.x >> 6;
  int wm = w >> 1, wn = w & 1;
  int r0 = m0 + 64 * wm, c0 = n0 + 64 * wn;
  int lr = l & 15, lk = (l >> 4) * 8;
  f32x4 acc[4][4] = {};
  for (int kk = 0; kk < 16; ++kk) {
    int k = kk * 32 + lk;
    bf16x8 a[4], b[4];
#pragma unroll
    for (int mf = 0; mf < 4; ++mf)
      a[mf] = ld_a(Xb, r0 + 16 * mf + lr, t0c, k);
#pragma unroll
    for (int nf = 0; nf < 4; ++nf)
      b[nf] = *(const bf16x8*)(Wa + (size_t)(c0 + 16 * nf + lr) * Dd + k);
#pragma unroll
    for (int mf = 0; mf < 4; ++mf)
#pragma unroll
      for (int nf = 0; nf < 4; ++nf)
        acc[mf][nf] = __builtin_amdgcn_mfma_f32_16x16x32_bf16(a[mf], b[nf], acc[mf][nf], 0, 0, 0);
  }
  int ri = (l >> 4) * 4;
  for (int mf = 0; mf < 4; ++mf) {
    int rowb = r0 + 16 * mf + ri;
    int pd[4];
#pragma unroll
    for (int i = 0; i < 4; ++i) {
      int rr = rowb + i;
      pd[i] = pid[(size_t)(rr >> 5) * Tt + t0c + (rr & 31)];
    }
    for (int nf = 0; nf < 4; ++nf) {
      int g = c0 + 16 * nf + lr;
      float bi = bih[g];
#pragma unroll
      for (int i = 0; i < 4; ++i) {
        float v = acc[mf][nf][i] + bi;
        if (pd[i] >= 0) v += b2f(WcT[(size_t)pd[i] * G3 + g]);
        gx[(size_t)(rowb + i) * G3 + g] = f2b(v);
      }
    }
  }
}

__global__ __launch_bounds__(256) void k_gates(const unsigned short* __restrict__ Xb,
                                               const unsigned short* __restrict__ Wa,
                                               const unsigned short* __restrict__ WcT,
                                               const float* __restrict__ bih,
                                               const int* __restrict__ pid,
                                               unsigned short* __restrict__ gx, int t0c) {
  gates_tile(blockIdx.x, blockIdx.y, Xb, Wa, WcT, bih, pid, gx, t0c);
}

// ---------------- logits tile ----------------
DEVI void logits_tile(int blk, const unsigned short* __restrict__ hsc,
                      const unsigned short* __restrict__ Wo,
                      const float* __restrict__ bout,
                      float* __restrict__ out, int t0) {
  int l = threadIdx.x & 63, w = threadIdx.x >> 6;
  int lr = l & 15, lk = (l >> 4) * 8;
  int r0 = blk * 64 + 16 * w;
  f32x4 acc[8] = {};
  for (int kk = 0; kk < 32; ++kk) {
    int k = kk * 32 + lk;
    bf16x8 a = *(const bf16x8*)(hsc + (size_t)(r0 + lr) * Hh + k);
#pragma unroll
    for (int nf = 0; nf < 8; ++nf) {
      bf16x8 b = *(const bf16x8*)(Wo + (size_t)(16 * nf + lr) * Hh + k);
      acc[nf] = __builtin_amdgcn_mfma_f32_16x16x32_bf16(a, b, acc[nf], 0, 0, 0);
    }
  }
  int ri = (l >> 4) * 4;
  for (int nf = 0; nf < 8; ++nf) {
    int c = 16 * nf + lr;
    float bo = bout[c];
#pragma unroll
    for (int i = 0; i < 4; ++i) {
      int m = r0 + ri + i;
      int grow = (m >> 5) * Tt + t0 + (m & 31);
      out[(size_t)grow * Cc + c] = acc[nf][i] + bo;
    }
  }
}

// ---------------- combo: gates(c+1) + logits(c) in one dispatch ----------------
__global__ __launch_bounds__(256) void k_combo(
    const unsigned short* __restrict__ Xb, const unsigned short* __restrict__ Wa,
    const unsigned short* __restrict__ WcT, const float* __restrict__ bih,
    const int* __restrict__ pid, unsigned short* __restrict__ gxNext, int doGates,
    const unsigned short* __restrict__ hsc, const unsigned short* __restrict__ Wob,
    const float* __restrict__ bou, float* __restrict__ outp, int t0) {
  int bid = blockIdx.x;
  if (bid < 1536) {
    if (doGates)
      gates_tile(bid & 63, bid >> 6, Xb, Wa, WcT, bih, pid, gxNext, t0 + TC);
  } else {
    logits_tile(bid - 1536, hsc, Wob, bou, outp, t0);
  }
}

// ---------------- recurrent scan chunk (round-10 proven) ----------------
// 256 blocks x 256 threads. mg = bid&7 (group/XCD, rows [32mg,+32)),
// cb = bid>>3 (hcols [32cb,+32)). Wave w: K-slice [256w,+256).
// notify[mg][32] epoch words; ALL waves poll (no sleep, no post-poll barrier).
__global__ __launch_bounds__(256, 1) void k_scan(const unsigned short* __restrict__ Whh,
                                                 const float* __restrict__ bhh,
                                                 const unsigned short* __restrict__ gx,
                                                 unsigned short* __restrict__ hring,
                                                 unsigned short* __restrict__ hsc,
                                                 unsigned int* __restrict__ notify,
                                                 int t0) {
  __shared__ float red[4 * 32 * 100];  // [wave][row32][3*32 pad100] = 51.2KB
  const int tid = threadIdx.x;
  const int l = tid & 63, w = tid >> 6;
  const int bid = blockIdx.x;
  const int mg = bid & 7, cb = bid >> 3;
  const int lr = l & 15, lk = (l >> 4) * 8;
  const int hcolBase = 32 * cb;
  const int ri = (l >> 4) * 4;

  // resident W_hh fragments: 3 gates x 2 col-halves x 8 k-steps
  bf16x8 Breg[6][8];
#pragma unroll
  for (int nf = 0; nf < 6; ++nf) {
    int wrow = (nf >> 1) * Hh + hcolBase + (nf & 1) * 16 + lr;
#pragma unroll
    for (int kk = 0; kk < 8; ++kk) {
      int k = 256 * w + 32 * kk + lk;
      Breg[nf][kk] = *(const bf16x8*)(Whh + (size_t)wrow * Hh + k);
    }
  }

  // epilogue mapping: thread -> 1 row x 4 cols (8-byte h I/O)
  const int erow = tid >> 3, ej0 = (tid & 7) * 4;
  const int eb = 32 * mg + erow;
  const int ecol = hcolBase + ej0;
  const float4 bhr4 = *(const float4*)(bhh + ecol);
  const float4 bhz4 = *(const float4*)(bhh + Hh + ecol);
  const float4 bhn4 = *(const float4*)(bhh + 2 * Hh + ecol);

  u64 hsave = 0;  // own h slice carried in registers across steps

  for (int tl = 0; tl < TC; ++tl) {
    const int t = t0 + tl;
    const unsigned short* hcur = hring + (size_t)(t % SLOTS) * (Bb * Hh);
    u64* hnq = (u64*)hring + (size_t)((t + 1) % SLOTS) * (Bb * Hh / 4);

    // prefetch gx for this step (independent of the wait)
    const size_t gxo = (size_t)(eb * TC + tl) * G3;
    uint2 gr = *(const uint2*)(gx + gxo + ecol);
    uint2 gz = *(const uint2*)(gx + gxo + Hh + ecol);
    uint2 gn = *(const uint2*)(gx + gxo + 2 * Hh + ecol);

    // wait: all 32 blocks of this group produced h[t]; every wave polls
    if (t > 0) {
      const unsigned int* np = notify + (mg << 6) + (l & 31);
      for (;;) {
        unsigned int v = __hip_atomic_load(np, __ATOMIC_RELAXED,
                                           __HIP_MEMORY_SCOPE_AGENT);
        if (__all((int)(v >= (unsigned)t))) break;
      }
    }
    asm volatile("" ::: "memory");

    u64 hprev = (tl == 0) ? *(const u64*)(hcur + (size_t)eb * Hh + ecol) : hsave;

    f32x4 acc[2][6] = {};
#pragma unroll
    for (int kk = 0; kk < 8; ++kk) {
      int k = 256 * w + 32 * kk + lk;
      bf16x8 a[2];
#pragma unroll
      for (int mf = 0; mf < 2; ++mf)
        a[mf] = *(const bf16x8*)(hcur + (size_t)(32 * mg + 16 * mf + lr) * Hh + k);
#pragma unroll
      for (int mf = 0; mf < 2; ++mf)
#pragma unroll
        for (int nf = 0; nf < 6; ++nf)
          acc[mf][nf] = __builtin_amdgcn_mfma_f32_16x16x32_bf16(a[mf], Breg[nf][kk], acc[mf][nf], 0, 0, 0);
    }

    // partials -> LDS (col = gate*32 + half*16 + lr)
#pragma unroll
    for (int mf = 0; mf < 2; ++mf)
#pragma unroll
      for (int nf = 0; nf < 6; ++nf)
#pragma unroll
        for (int i = 0; i < 4; ++i)
          red[(w * 32 + 16 * mf + ri + i) * 100 + (nf >> 1) * 32 + (nf & 1) * 16 + lr] = acc[mf][nf][i];
    __syncthreads();

    // reduce 4 wave-partials + gate math, 1 row x 4 cols per thread
    f32x4 vr = {}, vz = {}, vn = {};
#pragma unroll
    for (int w2 = 0; w2 < 4; ++w2) {
      const float* rp = &red[(w2 * 32 + erow) * 100];
      vr += *(const f32x4*)(rp + ej0);
      vz += *(const f32x4*)(rp + 32 + ej0);
      vn += *(const f32x4*)(rp + 64 + ej0);
    }
    unsigned short grs[4] = {(unsigned short)gr.x, (unsigned short)(gr.x >> 16),
                             (unsigned short)gr.y, (unsigned short)(gr.y >> 16)};
    unsigned short gzs[4] = {(unsigned short)gz.x, (unsigned short)(gz.x >> 16),
                             (unsigned short)gz.y, (unsigned short)(gz.y >> 16)};
    unsigned short gns[4] = {(unsigned short)gn.x, (unsigned short)(gn.x >> 16),
                             (unsigned short)gn.y, (unsigned short)(gn.y >> 16)};
    u64 ho = 0;
#pragma unroll
    for (int i = 0; i < 4; ++i) {
      float hr = vr[i] + (&bhr4.x)[i];
      float hz = vz[i] + (&bhz4.x)[i];
      float hn = vn[i] + (&bhn4.x)[i];
      float xr = b2f(grs[i]), xz = b2f(gzs[i]), xn = b2f(gns[i]);
      float rg = 1.f / (1.f + __expf(-(xr + hr)));
      float zg = 1.f / (1.f + __expf(-(xz + hz)));
      float pre = xn + rg * hn;
      pre = fminf(fmaxf(pre, -15.f), 15.f);
      float e = __expf(-2.f * pre);
      float ng = (1.f - e) / (1.f + e);
      float hp = b2f((unsigned short)(hprev >> (16 * i)));
      float hv = (1.f - zg) * ng + zg * hp;
      ho |= (u64)f2b(hv) << (16 * i);
    }
    // h output: MALL-visible store (consumers' caches hold no copy of this line)
    __hip_atomic_store(hnq + ((size_t)eb * Hh + ecol) / 4, ho,
                       __ATOMIC_RELAXED, __HIP_MEMORY_SCOPE_AGENT);
    hsave = ho;

    asm volatile("s_waitcnt vmcnt(0)" ::: "memory");  // h stores acked at MALL
    __syncthreads();  // all waves drained; also protects red[] reuse
    if (tid == 0)
      __hip_atomic_store(notify + (mg << 6) + cb, (unsigned)(t + 1),
                         __ATOMIC_RELAXED, __HIP_MEMORY_SCOPE_AGENT);
    // history write AFTER notify -- off the critical path
    *(u64*)(hsc + (size_t)(eb * TC + tl) * Hh + ecol) = ho;
  }
}

// ---------------- launch ----------------
extern "C" void kernel_launch(void* const* d_in, const int* in_sizes, int n_in,
                              void* d_out, int out_size, void* d_ws, size_t ws_size,
                              hipStream_t stream) {
  const float* gru = (const float*)d_in[0];
  const float* ts  = (const float*)d_in[1];
  const float* Wih = (const float*)d_in[2];
  const float* bih = (const float*)d_in[3];
  const float* Whh = (const float*)d_in[4];
  const float* bhh = (const float*)d_in[5];
  const float* Wou = (const float*)d_in[6];
  const float* bou = (const float*)d_in[7];
  float* out = (float*)d_out;

  char* ws = (char*)d_ws;
  size_t off = 0;
  auto alloc = [&](size_t bytes) -> void* {
    void* p = ws + off;
    off += (bytes + 255) & ~(size_t)255;
    return p;
  };
  unsigned short* Wa    = (unsigned short*)alloc((size_t)G3 * Dd * 2);        // 3.1MB
  unsigned short* WcT   = (unsigned short*)alloc((size_t)Cc * G3 * 2);        // 0.8MB
  unsigned short* Whb   = (unsigned short*)alloc((size_t)G3 * Hh * 2);        // 6.3MB
  unsigned short* Wob   = (unsigned short*)alloc((size_t)Cc * Hh * 2);        // 0.26MB
  int*            pid   = (int*)alloc((size_t)Bb * Tt * 4);                   // 0.26MB
  unsigned short* hring = (unsigned short*)alloc((size_t)SLOTS * Bb * Hh * 2);// 17.3MB
  unsigned int*   nfy   = (unsigned int*)alloc((size_t)8 * 64 * 4);
  unsigned short* Xb    = (unsigned short*)alloc((size_t)Bb * Tt * Dd * 2);   // 67.1MB
  unsigned short* gx    = (unsigned short*)alloc((size_t)Bb * TC * G3 * 2);   // 50.3MB
  unsigned short* hsc   = (unsigned short*)alloc((size_t)Bb * TC * Hh * 2);   // 16.8MB
  if (ws_size < off) return;  // ~155MiB total; round-9 proved >=163MiB exists

  int nX = Bb * Tt * Dd;
  k_cvt<<<nX / 2048, 256, 0, stream>>>(gru, Xb, nX);
  k_cvt<<<(G3 * Hh) / 2048, 256, 0, stream>>>(Whh, Whb, G3 * Hh);
  k_cvt<<<(Cc * Hh) / 2048, 256, 0, stream>>>(Wou, Wob, Cc * Hh);
  k_cvt_wa<<<(G3 * 64) / 256, 256, 0, stream>>>(Wih, Wa);
  k_cvt_wct<<<dim3(G3 / 256, Cc), 256, 0, stream>>>(Wih, WcT);
  k_pid<<<(Bb * Tt) / 256, 256, 0, stream>>>(ts, pid);
  hipMemsetAsync(hring, 0, (size_t)Bb * Hh * 2, stream);  // slot 0 = h(0) = 0
  hipMemsetAsync(nfy, 0, (size_t)8 * 64 * 4, stream);

  // prologue: gates for chunk 0
  k_gates<<<dim3(64, 24), 256, 0, stream>>>(Xb, Wa, WcT, bih, pid, gx, 0);

  for (int c = 0; c < NC; ++c) {
    int t0 = c * TC;
    k_scan<<<dim3(256), dim3(256), 0, stream>>>(Whb, bhh, gx, hring, hsc, nfy, t0);
    k_combo<<<dim3(1664), dim3(256), 0, stream>>>(
        Xb, Wa, WcT, bih, pid, gx, (c + 1 < NC) ? 1 : 0,
        hsc, Wob, bou, out, t0);
  }
}